// Round 2
// baseline (292.046 us; speedup 1.0000x reference)
//
#include <hip/hip_runtime.h>

// ---------- types & helpers ----------
typedef short bf16x8 __attribute__((ext_vector_type(8)));   // 8 bf16 (4 VGPRs)
typedef float f32x4 __attribute__((ext_vector_type(4)));

__device__ __forceinline__ unsigned short f2bf(float f) {
  union { float f; unsigned u; } x; x.f = f;
  unsigned u = x.u;
  u += 0x7fffu + ((u >> 16) & 1u);      // round-to-nearest-even
  return (unsigned short)(u >> 16);
}

// ---------- 1. f32 -> bf16 conversion of all operands ----------
__global__ __launch_bounds__(256) void cvt_all(
    const float* __restrict__ text, const float* __restrict__ vis,
    const float* __restrict__ wq, const float* __restrict__ wk,
    const float* __restrict__ wv, const float* __restrict__ wo,
    unsigned short* __restrict__ o0, unsigned short* __restrict__ o1,
    unsigned short* __restrict__ o2, unsigned short* __restrict__ o3,
    unsigned short* __restrict__ o4, unsigned short* __restrict__ o5)
{
  long i4 = (long)blockIdx.x * 256 + threadIdx.x;   // index in float4 units
  const float* src; unsigned short* dst; long base;
  if      (i4 <   65536) { src = text; dst = o0; base = 0; }
  else if (i4 <  851968) { src = vis;  dst = o1; base = 65536; }
  else if (i4 < 1114112) { src = wq;   dst = o2; base = 851968; }
  else if (i4 < 1376256) { src = wk;   dst = o3; base = 1114112; }
  else if (i4 < 1638400) { src = wv;   dst = o4; base = 1376256; }
  else                   { src = wo;   dst = o5; base = 1638400; }
  long li = i4 - base;
  float4 f = reinterpret_cast<const float4*>(src)[li];
  uint2 u;
  u.x = (unsigned)f2bf(f.x) | ((unsigned)f2bf(f.y) << 16);
  u.y = (unsigned)f2bf(f.z) | ((unsigned)f2bf(f.w) << 16);
  reinterpret_cast<uint2*>(dst)[li] = u;
}

// ---------- 2. generic bf16 GEMM  C[M,N] = A[M,K] @ B[N,K]^T (+bias), bf16 out ----------
// block = 256 thr = 4 waves; tile 64x64, BK=32; wave w -> 32x32 subtile (2x2 frags)
__global__ __launch_bounds__(256) void gemm_abt_bf16(
    const unsigned short* __restrict__ A,
    const unsigned short* __restrict__ B,
    unsigned short* __restrict__ C,
    const float* __restrict__ bias,
    int K, int lda, int ldb, int ldc)
{
  __shared__ unsigned short As[64][40];   // +8 pad
  __shared__ unsigned short Bs[64][40];
  const int m0 = blockIdx.y * 64, n0 = blockIdx.x * 64;
  const int tid = threadIdx.x;
  const int lane = tid & 63, w = tid >> 6;
  const int wm = w >> 1, wn = w & 1;
  const int r16 = lane & 15, kg = lane >> 4;
  const int srow = tid >> 2, sseg = tid & 3;

  const f32x4 fzero = {0.f, 0.f, 0.f, 0.f};
  f32x4 acc[2][2];
#pragma unroll
  for (int i = 0; i < 2; ++i)
#pragma unroll
    for (int j = 0; j < 2; ++j) acc[i][j] = fzero;

  for (int k0 = 0; k0 < K; k0 += 32) {
    __syncthreads();
    *reinterpret_cast<int4*>(&As[srow][sseg * 8]) =
        *reinterpret_cast<const int4*>(&A[(long)(m0 + srow) * lda + k0 + sseg * 8]);
    *reinterpret_cast<int4*>(&Bs[srow][sseg * 8]) =
        *reinterpret_cast<const int4*>(&B[(long)(n0 + srow) * ldb + k0 + sseg * 8]);
    __syncthreads();
    bf16x8 a[2], b[2];
#pragma unroll
    for (int i = 0; i < 2; ++i)
      a[i] = *reinterpret_cast<const bf16x8*>(&As[wm * 32 + i * 16 + r16][kg * 8]);
#pragma unroll
    for (int j = 0; j < 2; ++j)
      b[j] = *reinterpret_cast<const bf16x8*>(&Bs[wn * 32 + j * 16 + r16][kg * 8]);
#pragma unroll
    for (int i = 0; i < 2; ++i)
#pragma unroll
      for (int j = 0; j < 2; ++j)
        acc[i][j] = __builtin_amdgcn_mfma_f32_16x16x32_bf16(a[i], b[j], acc[i][j], 0, 0, 0);
  }
  // epilogue: D row = (lane>>4)*4 + r, col = lane&15   (m89-verified layout)
#pragma unroll
  for (int i = 0; i < 2; ++i) {
#pragma unroll
    for (int j = 0; j < 2; ++j) {
      const int row = m0 + wm * 32 + i * 16 + kg * 4;
      const int col = n0 + wn * 32 + j * 16 + r16;
      const float bv = bias ? bias[col] : 0.f;
#pragma unroll
      for (int r = 0; r < 4; ++r)
        C[(long)(row + r) * ldc + col] = f2bf(acc[i][j][r] + bv);
    }
  }
}

// ---------- 3. scores + softmax over frames -> P[v][t][f*16+h] (bf16) ----------
// block per (h,v): D1[f(12,pad16)][t(256)] = K_vh(12x64) @ Q_h(256x64)^T via MFMA,
// softmax over f via cross-lane (kg-group) reduction.
__global__ __launch_bounds__(256) void scores_softmax(
    const unsigned short* __restrict__ Kp,   // [v*12][1024] = [v][f][h*64+d]
    const unsigned short* __restrict__ Qp,   // [256][1024]  = [t][h*64+d]
    unsigned short* __restrict__ P)          // [v][256][192]
{
  const int h = blockIdx.x, v = blockIdx.y;
  const int tid = threadIdx.x, lane = tid & 63, w = tid >> 6;
  const int r16 = lane & 15, kg = lane >> 4;
  __shared__ unsigned short Ks[16][72];
  __shared__ unsigned short Qs[256][72];

  if (tid < 96) {
    const int f = tid >> 3, seg = tid & 7;
    *reinterpret_cast<int4*>(&Ks[f][seg * 8]) =
        *reinterpret_cast<const int4*>(&Kp[(long)(v * 12 + f) * 1024 + h * 64 + seg * 8]);
  } else if (tid < 128) {   // zero-fill pad rows 12..15
    const int f = 12 + ((tid - 96) >> 3), seg = (tid - 96) & 7;
    int4 z; z.x = z.y = z.z = z.w = 0;
    *reinterpret_cast<int4*>(&Ks[f][seg * 8]) = z;
  }
#pragma unroll
  for (int rep = 0; rep < 8; ++rep) {
    const int row = rep * 32 + (tid >> 3), seg = tid & 7;
    *reinterpret_cast<int4*>(&Qs[row][seg * 8]) =
        *reinterpret_cast<const int4*>(&Qp[(long)row * 1024 + h * 64 + seg * 8]);
  }
  __syncthreads();

  const f32x4 fzero = {0.f, 0.f, 0.f, 0.f};
  f32x4 acc[4];
#pragma unroll
  for (int j = 0; j < 4; ++j) acc[j] = fzero;

#pragma unroll
  for (int kk = 0; kk < 64; kk += 32) {
    bf16x8 a = *reinterpret_cast<const bf16x8*>(&Ks[r16][kk + kg * 8]);
#pragma unroll
    for (int j = 0; j < 4; ++j) {
      bf16x8 b = *reinterpret_cast<const bf16x8*>(&Qs[w * 64 + j * 16 + r16][kk + kg * 8]);
      acc[j] = __builtin_amdgcn_mfma_f32_16x16x32_bf16(a, b, acc[j], 0, 0, 0);
    }
  }
  // rows f = kg*4+r (valid f<12), col t = w*64 + j*16 + r16
#pragma unroll
  for (int j = 0; j < 4; ++j) {
    float lm = -1e30f;
    if (kg < 3) {
#pragma unroll
      for (int r = 0; r < 4; ++r) lm = fmaxf(lm, acc[j][r] * 0.125f);
    }
    lm = fmaxf(lm, __shfl_xor(lm, 16));
    lm = fmaxf(lm, __shfl_xor(lm, 32));
    float p[4]; float ls = 0.f;
    if (kg < 3) {
#pragma unroll
      for (int r = 0; r < 4; ++r) { p[r] = __expf(acc[j][r] * 0.125f - lm); ls += p[r]; }
    }
    ls += __shfl_xor(ls, 16);
    ls += __shfl_xor(ls, 32);
    const float inv = 1.f / ls;
    if (kg < 3) {
      const int t = w * 64 + j * 16 + r16;
#pragma unroll
      for (int r = 0; r < 4; ++r)
        P[((long)v * 256 + t) * 192 + (kg * 4 + r) * 16 + h] = f2bf(p[r] * inv);
    }
  }
}

// ---------- 4. fused Zh + combine:  out[v][t][o] = sum_k P[v][t][k] * Zh_v[k][o] + bo ----------
// grid (o-tile=16, v=256), block 256 thr = 4 waves; tile = 256 t x 64 o.
// Phase 1: per h, Zh slice (12 f x 64 o) via MFMA -> BsAll[o][k=f*16+h] (bf16, LDS).
// Phase 2: K=192 GEMM, wave w owns t-rows [w*64, w*64+64).
__global__ __launch_bounds__(256) void combine(
    const unsigned short* __restrict__ VPp,  // [v*12][1024] = [v][f][h*64+d]
    const unsigned short* __restrict__ Wo,   // [1024][1024] bf16
    const unsigned short* __restrict__ P,    // [v][256][192]
    const float* __restrict__ bo,
    float* __restrict__ out)                 // [v][256][1024]
{
  const int n0 = blockIdx.x * 64, v = blockIdx.y;
  const int tid = threadIdx.x, lane = tid & 63, w = tid >> 6;
  const int r16 = lane & 15, kg = lane >> 4;
  __shared__ unsigned short BsAll[64][200];    // [o_local][k], 25.6 KB, persistent
  __shared__ unsigned short Scr[10240];        // phase1: VPh[16][72] + WoT[64][72]; phase2: As[256][40]

  // ---- phase 1: build Zh slice for this (v, o-tile) ----
  for (int h = 0; h < 16; ++h) {
    __syncthreads();
    if (tid < 96) {     // VPh: 12 rows x 64 d
      const int f = tid >> 3, seg = tid & 7;
      *reinterpret_cast<int4*>(&Scr[f * 72 + seg * 8]) =
          *reinterpret_cast<const int4*>(&VPp[(long)(v * 12 + f) * 1024 + h * 64 + seg * 8]);
    } else if (tid < 128) {   // zero-fill pad rows 12..15 (A-fragment reads them)
      const int f = 12 + ((tid - 96) >> 3), seg = (tid - 96) & 7;
      int4 z; z.x = z.y = z.z = z.w = 0;
      *reinterpret_cast<int4*>(&Scr[f * 72 + seg * 8]) = z;
    }
    {                   // WoT: 64 o-rows x 64 d  (512 int4 total -> 2 per thread)
      const int orow = tid >> 2;
#pragma unroll
      for (int rep = 0; rep < 2; ++rep) {
        const int seg = (tid & 3) + rep * 4;
        *reinterpret_cast<int4*>(&Scr[1152 + orow * 72 + seg * 8]) =
            *reinterpret_cast<const int4*>(&Wo[(long)(n0 + orow) * 1024 + h * 64 + seg * 8]);
      }
    }
    __syncthreads();
    f32x4 acc1 = {0.f, 0.f, 0.f, 0.f};
#pragma unroll
    for (int kk = 0; kk < 64; kk += 32) {
      bf16x8 a = *reinterpret_cast<const bf16x8*>(&Scr[r16 * 72 + kk + kg * 8]);
      bf16x8 b = *reinterpret_cast<const bf16x8*>(&Scr[1152 + (w * 16 + r16) * 72 + kk + kg * 8]);
      acc1 = __builtin_amdgcn_mfma_f32_16x16x32_bf16(a, b, acc1, 0, 0, 0);
    }
    // D1 rows f = kg*4+r (keep f<12), col o_local = w*16 + r16
#pragma unroll
    for (int r = 0; r < 4; ++r) {
      const int f = kg * 4 + r;
      if (f < 12) BsAll[w * 16 + r16][f * 16 + h] = f2bf(acc1[r]);
    }
  }

  // ---- phase 2: out tile = P_v @ BsAll^T ----
  const f32x4 fzero = {0.f, 0.f, 0.f, 0.f};
  f32x4 acc[4][4];
#pragma unroll
  for (int i = 0; i < 4; ++i)
#pragma unroll
    for (int j = 0; j < 4; ++j) acc[i][j] = fzero;

  for (int k0 = 0; k0 < 192; k0 += 32) {
    __syncthreads();
#pragma unroll
    for (int rep = 0; rep < 4; ++rep) {     // stage As: 256 t-rows x 32 k
      const int row = rep * 64 + (tid >> 2), seg = tid & 3;
      *reinterpret_cast<int4*>(&Scr[row * 40 + seg * 8]) =
          *reinterpret_cast<const int4*>(&P[((long)v * 256 + row) * 192 + k0 + seg * 8]);
    }
    __syncthreads();
    bf16x8 b[4];
#pragma unroll
    for (int j = 0; j < 4; ++j)
      b[j] = *reinterpret_cast<const bf16x8*>(&BsAll[j * 16 + r16][k0 + kg * 8]);
#pragma unroll
    for (int i = 0; i < 4; ++i) {
      bf16x8 a = *reinterpret_cast<const bf16x8*>(&Scr[(w * 64 + i * 16 + r16) * 40 + kg * 8]);
#pragma unroll
      for (int j = 0; j < 4; ++j)
        acc[i][j] = __builtin_amdgcn_mfma_f32_16x16x32_bf16(a, b[j], acc[i][j], 0, 0, 0);
    }
  }
#pragma unroll
  for (int i = 0; i < 4; ++i) {
#pragma unroll
    for (int j = 0; j < 4; ++j) {
      const int trow = w * 64 + i * 16 + kg * 4;
      const int col = n0 + j * 16 + r16;
      const float bv = bo[col];
#pragma unroll
      for (int r = 0; r < 4; ++r)
        out[((long)v * 256 + trow + r) * 1024 + col] = acc[i][j][r] + bv;
    }
  }
}

// ---------- launch ----------
extern "C" void kernel_launch(void* const* d_in, const int* in_sizes, int n_in,
                              void* d_out, int out_size, void* d_ws, size_t ws_size,
                              hipStream_t stream) {
  const float* text = (const float*)d_in[0];
  const float* vis  = (const float*)d_in[1];
  const float* wq   = (const float*)d_in[2];
  const float* bq   = (const float*)d_in[3];
  const float* wk   = (const float*)d_in[4];
  const float* bk   = (const float*)d_in[5];
  const float* wv   = (const float*)d_in[6];
  const float* bv   = (const float*)d_in[7];
  const float* wo   = (const float*)d_in[8];
  const float* bo   = (const float*)d_in[9];
  float* out = (float*)d_out;

  unsigned short* text16 = (unsigned short*)d_ws;      // 262144
  unsigned short* vis16  = text16 + 262144;            // 3145728
  unsigned short* wq16   = vis16  + 3145728;           // 1048576
  unsigned short* wk16   = wq16   + 1048576;           // 1048576
  unsigned short* wv16   = wk16   + 1048576;           // 1048576
  unsigned short* wo16   = wv16   + 1048576;           // 1048576
  unsigned short* q16    = wo16   + 1048576;           // 262144
  unsigned short* k16    = q16    + 262144;            // 3145728
  unsigned short* vp16   = k16    + 3145728;           // 3145728
  unsigned short* P      = vp16   + 3145728;           // 12582912  (total ~51 MB)

  cvt_all<<<7424, 256, 0, stream>>>(text, vis, wq, wk, wv, wo,
                                    text16, vis16, wq16, wk16, wv16, wo16);
  // q = text @ wq^T   [256 x 1024]
  gemm_abt_bf16<<<dim3(16, 4), 256, 0, stream>>>(text16, wq16, q16, bq, 1024, 1024, 1024, 1024);
  // k = vision @ wk^T [3072 x 1024]
  gemm_abt_bf16<<<dim3(16, 48), 256, 0, stream>>>(vis16, wk16, k16, bk, 1024, 1024, 1024, 1024);
  // vproj = vision @ wv^T [3072 x 1024]
  gemm_abt_bf16<<<dim3(16, 48), 256, 0, stream>>>(vis16, wv16, vp16, bv, 1024, 1024, 1024, 1024);
  // P[v][t][f*16+h] = softmax_f(k.q/8)
  scores_softmax<<<dim3(16, 256), 256, 0, stream>>>(k16, q16, P);
  // out = P @ Zh + bo (Zh fused)
  combine<<<dim3(16, 256), 256, 0, stream>>>(vp16, wo16, P, bo, out);
}

// Round 3
// 279.141 us; speedup vs baseline: 1.0462x; 1.0462x over previous
//
#include <hip/hip_runtime.h>

// ---------- types & helpers ----------
typedef short bf16x8 __attribute__((ext_vector_type(8)));   // 8 bf16 (4 VGPRs)
typedef float f32x4 __attribute__((ext_vector_type(4)));

__device__ __forceinline__ unsigned short f2bf(float f) {
  union { float f; unsigned u; } x; x.f = f;
  unsigned u = x.u;
  u += 0x7fffu + ((u >> 16) & 1u);      // round-to-nearest-even
  return (unsigned short)(u >> 16);
}

// ---------- 1. f32 -> bf16 conversion of all operands ----------
__global__ __launch_bounds__(256) void cvt_all(
    const float* __restrict__ text, const float* __restrict__ vis,
    const float* __restrict__ wq, const float* __restrict__ wk,
    const float* __restrict__ wv, const float* __restrict__ wo,
    unsigned short* __restrict__ o0, unsigned short* __restrict__ o1,
    unsigned short* __restrict__ o2, unsigned short* __restrict__ o3,
    unsigned short* __restrict__ o4, unsigned short* __restrict__ o5)
{
  long i4 = (long)blockIdx.x * 256 + threadIdx.x;   // index in float4 units
  const float* src; unsigned short* dst; long base;
  if      (i4 <   65536) { src = text; dst = o0; base = 0; }
  else if (i4 <  851968) { src = vis;  dst = o1; base = 65536; }
  else if (i4 < 1114112) { src = wq;   dst = o2; base = 851968; }
  else if (i4 < 1376256) { src = wk;   dst = o3; base = 1114112; }
  else if (i4 < 1638400) { src = wv;   dst = o4; base = 1376256; }
  else                   { src = wo;   dst = o5; base = 1638400; }
  long li = i4 - base;
  float4 f = reinterpret_cast<const float4*>(src)[li];
  uint2 u;
  u.x = (unsigned)f2bf(f.x) | ((unsigned)f2bf(f.y) << 16);
  u.y = (unsigned)f2bf(f.z) | ((unsigned)f2bf(f.w) << 16);
  reinterpret_cast<uint2*>(dst)[li] = u;
}

// ---------- 2. generic bf16 GEMM  C[M,N] = A[M,K] @ B[N,K]^T (+bias), bf16 out ----------
__global__ __launch_bounds__(256) void gemm_abt_bf16(
    const unsigned short* __restrict__ A,
    const unsigned short* __restrict__ B,
    unsigned short* __restrict__ C,
    const float* __restrict__ bias,
    int K, int lda, int ldb, int ldc)
{
  __shared__ unsigned short As[64][40];   // +8 pad
  __shared__ unsigned short Bs[64][40];
  const int m0 = blockIdx.y * 64, n0 = blockIdx.x * 64;
  const int tid = threadIdx.x;
  const int lane = tid & 63, w = tid >> 6;
  const int wm = w >> 1, wn = w & 1;
  const int r16 = lane & 15, kg = lane >> 4;
  const int srow = tid >> 2, sseg = tid & 3;

  const f32x4 fzero = {0.f, 0.f, 0.f, 0.f};
  f32x4 acc[2][2];
#pragma unroll
  for (int i = 0; i < 2; ++i)
#pragma unroll
    for (int j = 0; j < 2; ++j) acc[i][j] = fzero;

  for (int k0 = 0; k0 < K; k0 += 32) {
    __syncthreads();
    *reinterpret_cast<int4*>(&As[srow][sseg * 8]) =
        *reinterpret_cast<const int4*>(&A[(long)(m0 + srow) * lda + k0 + sseg * 8]);
    *reinterpret_cast<int4*>(&Bs[srow][sseg * 8]) =
        *reinterpret_cast<const int4*>(&B[(long)(n0 + srow) * ldb + k0 + sseg * 8]);
    __syncthreads();
    bf16x8 a[2], b[2];
#pragma unroll
    for (int i = 0; i < 2; ++i)
      a[i] = *reinterpret_cast<const bf16x8*>(&As[wm * 32 + i * 16 + r16][kg * 8]);
#pragma unroll
    for (int j = 0; j < 2; ++j)
      b[j] = *reinterpret_cast<const bf16x8*>(&Bs[wn * 32 + j * 16 + r16][kg * 8]);
#pragma unroll
    for (int i = 0; i < 2; ++i)
#pragma unroll
      for (int j = 0; j < 2; ++j)
        acc[i][j] = __builtin_amdgcn_mfma_f32_16x16x32_bf16(a[i], b[j], acc[i][j], 0, 0, 0);
  }
#pragma unroll
  for (int i = 0; i < 2; ++i) {
#pragma unroll
    for (int j = 0; j < 2; ++j) {
      const int row = m0 + wm * 32 + i * 16 + kg * 4;
      const int col = n0 + wn * 32 + j * 16 + r16;
      const float bv = bias ? bias[col] : 0.f;
#pragma unroll
      for (int r = 0; r < 4; ++r)
        C[(long)(row + r) * ldc + col] = f2bf(acc[i][j][r] + bv);
    }
  }
}

// ---------- 3. scores + softmax over frames -> P[v][t][f*16+h] (bf16) ----------
__global__ __launch_bounds__(256) void scores_softmax(
    const unsigned short* __restrict__ Kp,   // [v*12][1024] = [v][f][h*64+d]
    const unsigned short* __restrict__ Qp,   // [256][1024]  = [t][h*64+d]
    unsigned short* __restrict__ P)          // [v][256][192]
{
  const int h = blockIdx.x, v = blockIdx.y;
  const int tid = threadIdx.x, lane = tid & 63, w = tid >> 6;
  const int r16 = lane & 15, kg = lane >> 4;
  __shared__ unsigned short Ks[16][72];
  __shared__ unsigned short Qs[256][72];

  if (tid < 96) {
    const int f = tid >> 3, seg = tid & 7;
    *reinterpret_cast<int4*>(&Ks[f][seg * 8]) =
        *reinterpret_cast<const int4*>(&Kp[(long)(v * 12 + f) * 1024 + h * 64 + seg * 8]);
  } else if (tid < 128) {   // zero-fill pad rows 12..15
    const int f = 12 + ((tid - 96) >> 3), seg = (tid - 96) & 7;
    int4 z; z.x = z.y = z.z = z.w = 0;
    *reinterpret_cast<int4*>(&Ks[f][seg * 8]) = z;
  }
#pragma unroll
  for (int rep = 0; rep < 8; ++rep) {
    const int row = rep * 32 + (tid >> 3), seg = tid & 7;
    *reinterpret_cast<int4*>(&Qs[row][seg * 8]) =
        *reinterpret_cast<const int4*>(&Qp[(long)row * 1024 + h * 64 + seg * 8]);
  }
  __syncthreads();

  const f32x4 fzero = {0.f, 0.f, 0.f, 0.f};
  f32x4 acc[4];
#pragma unroll
  for (int j = 0; j < 4; ++j) acc[j] = fzero;

#pragma unroll
  for (int kk = 0; kk < 64; kk += 32) {
    bf16x8 a = *reinterpret_cast<const bf16x8*>(&Ks[r16][kk + kg * 8]);
#pragma unroll
    for (int j = 0; j < 4; ++j) {
      bf16x8 b = *reinterpret_cast<const bf16x8*>(&Qs[w * 64 + j * 16 + r16][kk + kg * 8]);
      acc[j] = __builtin_amdgcn_mfma_f32_16x16x32_bf16(a, b, acc[j], 0, 0, 0);
    }
  }
#pragma unroll
  for (int j = 0; j < 4; ++j) {
    float lm = -1e30f;
    if (kg < 3) {
#pragma unroll
      for (int r = 0; r < 4; ++r) lm = fmaxf(lm, acc[j][r] * 0.125f);
    }
    lm = fmaxf(lm, __shfl_xor(lm, 16));
    lm = fmaxf(lm, __shfl_xor(lm, 32));
    float p[4]; float ls = 0.f;
    if (kg < 3) {
#pragma unroll
      for (int r = 0; r < 4; ++r) { p[r] = __expf(acc[j][r] * 0.125f - lm); ls += p[r]; }
    }
    ls += __shfl_xor(ls, 16);
    ls += __shfl_xor(ls, 32);
    const float inv = 1.f / ls;
    if (kg < 3) {
      const int t = w * 64 + j * 16 + r16;
#pragma unroll
      for (int r = 0; r < 4; ++r)
        P[((long)v * 256 + t) * 192 + (kg * 4 + r) * 16 + h] = f2bf(p[r] * inv);
    }
  }
}

// ---------- 4. fused Zh + combine (restructured) ----------
// Grid: 4096 1-D blocks, XCD-swizzled so all 16 o-tiles of a v share an XCD.
// Phase 1 (8 iters, 2 h each): Zh slice -> BsAll[64 o][192 k], T2-swizzled LDS.
// Phase 2 (barrier-free): acc[4][4] per wave; A-frags read DIRECTLY from global P
// (L2-resident), B-frags from BsAll. One barrier between phases.
__global__ __launch_bounds__(256) void combine(
    const unsigned short* __restrict__ VPp,  // [v*12][1024] = [v][f][h*64+d]
    const unsigned short* __restrict__ Wo,   // [1024][1024] bf16
    const unsigned short* __restrict__ P,    // [v][256][192]
    const float* __restrict__ bo,
    float* __restrict__ out)                 // [v][256][1024]
{
  // XCD-aware bijective swizzle: 4096 = 8 xcd * 32 vgrp * 16 otile
  const int wgid = blockIdx.x;
  const int xcd = wgid & 7, idx = wgid >> 3;
  const int v = ((idx & 31) << 3) | xcd;
  const int n0 = (idx >> 5) << 6;

  const int tid = threadIdx.x, lane = tid & 63, w = tid >> 6;
  const int r16 = lane & 15, kg = lane >> 4;

  // All tiles T2-swizzled: 16B slot' = slot ^ (row & 7)
  __shared__ unsigned short BsAll[64 * 192];   // [o][k]   24.0 KB
  __shared__ unsigned short VPs[2][16 * 64];   // [f][d]    4.0 KB
  __shared__ unsigned short Wos[2][64 * 64];   // [o][d]   16.0 KB

  // ---- phase 1: build Zh slice (2 h per iteration) ----
  for (int it = 0; it < 8; ++it) {
    const int hbase = it * 2;
    __syncthreads();
    {   // VP staging: 2 tiles x 16 rows x 8 slots = 256 int4 (1/thread)
      const int hh = tid >> 7, row = (tid >> 3) & 15, slot = tid & 7;
      int4 val;
      if (row < 12)
        val = *reinterpret_cast<const int4*>(
            &VPp[(long)(v * 12 + row) * 1024 + (hbase + hh) * 64 + slot * 8]);
      else { val.x = 0; val.y = 0; val.z = 0; val.w = 0; }
      *reinterpret_cast<int4*>(&VPs[hh][row * 64 + ((slot ^ (row & 7)) << 3)]) = val;
    }
    {   // Wo staging: 2 tiles x 64 rows x 8 slots = 1024 int4 (4/thread)
      const int hh = tid >> 7;
      const int row = (tid & 127) >> 1, slot0 = (tid & 1) * 4;
#pragma unroll
      for (int rep = 0; rep < 4; ++rep) {
        const int slot = slot0 + rep;
        *reinterpret_cast<int4*>(&Wos[hh][row * 64 + ((slot ^ (row & 7)) << 3)]) =
            *reinterpret_cast<const int4*>(
                &Wo[(long)(n0 + row) * 1024 + (hbase + hh) * 64 + slot * 8]);
      }
    }
    __syncthreads();
    // wave w: hh = w>>1, o-half = w&1; D1[f(12)][o(32)] slice
    const int hh = w >> 1, oh = w & 1, h = hbase + hh;
    f32x4 accp[2] = {{0.f,0.f,0.f,0.f},{0.f,0.f,0.f,0.f}};
#pragma unroll
    for (int kk = 0; kk < 64; kk += 32) {
      const int slot = (kk >> 3) + kg;
      bf16x8 a = *reinterpret_cast<const bf16x8*>(
          &VPs[hh][r16 * 64 + ((slot ^ (r16 & 7)) << 3)]);
#pragma unroll
      for (int j = 0; j < 2; ++j) {
        const int orow = oh * 32 + j * 16 + r16;
        bf16x8 b = *reinterpret_cast<const bf16x8*>(
            &Wos[hh][orow * 64 + ((slot ^ (orow & 7)) << 3)]);
        accp[j] = __builtin_amdgcn_mfma_f32_16x16x32_bf16(a, b, accp[j], 0, 0, 0);
      }
    }
    // D rows f = kg*4+r (keep f<12), col o = oh*32 + j*16 + r16
#pragma unroll
    for (int j = 0; j < 2; ++j) {
#pragma unroll
      for (int r = 0; r < 4; ++r) {
        const int f = kg * 4 + r;
        if (f < 12) {
          const int o = oh * 32 + j * 16 + r16;
          const int k = f * 16 + h;
          BsAll[o * 192 + (((k >> 3) ^ (o & 7)) << 3) + (k & 7)] = f2bf(accp[j][r]);
        }
      }
    }
  }
  __syncthreads();

  // ---- phase 2: out tile = P_v @ BsAll^T (no barriers, no LDS A-staging) ----
  const f32x4 fzero = {0.f, 0.f, 0.f, 0.f};
  f32x4 acc[4][4];
#pragma unroll
  for (int i = 0; i < 4; ++i)
#pragma unroll
    for (int j = 0; j < 4; ++j) acc[i][j] = fzero;

  const unsigned short* Pv = P + (long)v * 256 * 192;
#pragma unroll
  for (int k0 = 0; k0 < 192; k0 += 32) {
    bf16x8 b[4];
#pragma unroll
    for (int j = 0; j < 4; ++j) {
      const int row = j * 16 + r16;
      const int slot = (k0 >> 3) + kg;
      b[j] = *reinterpret_cast<const bf16x8*>(
          &BsAll[row * 192 + ((slot ^ (row & 7)) << 3)]);
    }
#pragma unroll
    for (int i = 0; i < 4; ++i) {
      bf16x8 a = *reinterpret_cast<const bf16x8*>(
          &Pv[(long)(w * 64 + i * 16 + r16) * 192 + k0 + kg * 8]);
#pragma unroll
      for (int j = 0; j < 4; ++j)
        acc[i][j] = __builtin_amdgcn_mfma_f32_16x16x32_bf16(a, b[j], acc[i][j], 0, 0, 0);
    }
  }
#pragma unroll
  for (int i = 0; i < 4; ++i) {
#pragma unroll
    for (int j = 0; j < 4; ++j) {
      const int trow = w * 64 + i * 16 + kg * 4;
      const int col = n0 + j * 16 + r16;
      const float bv = bo[col];
#pragma unroll
      for (int r = 0; r < 4; ++r)
        out[((long)v * 256 + trow + r) * 1024 + col] = acc[i][j][r] + bv;
    }
  }
}

// ---------- launch ----------
extern "C" void kernel_launch(void* const* d_in, const int* in_sizes, int n_in,
                              void* d_out, int out_size, void* d_ws, size_t ws_size,
                              hipStream_t stream) {
  const float* text = (const float*)d_in[0];
  const float* vis  = (const float*)d_in[1];
  const float* wq   = (const float*)d_in[2];
  const float* bq   = (const float*)d_in[3];
  const float* wk   = (const float*)d_in[4];
  const float* bk   = (const float*)d_in[5];
  const float* wv   = (const float*)d_in[6];
  const float* bv   = (const float*)d_in[7];
  const float* wo   = (const float*)d_in[8];
  const float* bo   = (const float*)d_in[9];
  float* out = (float*)d_out;

  unsigned short* text16 = (unsigned short*)d_ws;      // 262144
  unsigned short* vis16  = text16 + 262144;            // 3145728
  unsigned short* wq16   = vis16  + 3145728;           // 1048576
  unsigned short* wk16   = wq16   + 1048576;           // 1048576
  unsigned short* wv16   = wk16   + 1048576;           // 1048576
  unsigned short* wo16   = wv16   + 1048576;           // 1048576
  unsigned short* q16    = wo16   + 1048576;           // 262144
  unsigned short* k16    = q16    + 262144;            // 3145728
  unsigned short* vp16   = k16    + 3145728;           // 3145728
  unsigned short* P      = vp16   + 3145728;           // 12582912  (total ~51 MB)

  cvt_all<<<7424, 256, 0, stream>>>(text, vis, wq, wk, wv, wo,
                                    text16, vis16, wq16, wk16, wv16, wo16);
  gemm_abt_bf16<<<dim3(16, 4), 256, 0, stream>>>(text16, wq16, q16, bq, 1024, 1024, 1024, 1024);
  gemm_abt_bf16<<<dim3(16, 48), 256, 0, stream>>>(vis16, wk16, k16, bk, 1024, 1024, 1024, 1024);
  gemm_abt_bf16<<<dim3(16, 48), 256, 0, stream>>>(vis16, wv16, vp16, bv, 1024, 1024, 1024, 1024);
  scores_softmax<<<dim3(16, 256), 256, 0, stream>>>(k16, q16, P);
  combine<<<4096, 256, 0, stream>>>(vp16, wo16, P, bo, out);
}

// Round 4
// 273.309 us; speedup vs baseline: 1.0686x; 1.0213x over previous
//
#include <hip/hip_runtime.h>

// ---------- types & helpers ----------
typedef short bf16x8 __attribute__((ext_vector_type(8)));   // 8 bf16 (4 VGPRs)
typedef float f32x4 __attribute__((ext_vector_type(4)));

__device__ __forceinline__ unsigned short f2bf(float f) {
  union { float f; unsigned u; } x; x.f = f;
  unsigned u = x.u;
  u += 0x7fffu + ((u >> 16) & 1u);      // round-to-nearest-even
  return (unsigned short)(u >> 16);
}

// ---------- 1. f32 -> bf16 conversion of all operands ----------
__global__ __launch_bounds__(256) void cvt_all(
    const float* __restrict__ text, const float* __restrict__ vis,
    const float* __restrict__ wq, const float* __restrict__ wk,
    const float* __restrict__ wv, const float* __restrict__ wo,
    unsigned short* __restrict__ o0, unsigned short* __restrict__ o1,
    unsigned short* __restrict__ o2, unsigned short* __restrict__ o3,
    unsigned short* __restrict__ o4, unsigned short* __restrict__ o5)
{
  long i4 = (long)blockIdx.x * 256 + threadIdx.x;   // index in float4 units
  const float* src; unsigned short* dst; long base;
  if      (i4 <   65536) { src = text; dst = o0; base = 0; }
  else if (i4 <  851968) { src = vis;  dst = o1; base = 65536; }
  else if (i4 < 1114112) { src = wq;   dst = o2; base = 851968; }
  else if (i4 < 1376256) { src = wk;   dst = o3; base = 1114112; }
  else if (i4 < 1638400) { src = wv;   dst = o4; base = 1376256; }
  else                   { src = wo;   dst = o5; base = 1638400; }
  long li = i4 - base;
  float4 f = reinterpret_cast<const float4*>(src)[li];
  uint2 u;
  u.x = (unsigned)f2bf(f.x) | ((unsigned)f2bf(f.y) << 16);
  u.y = (unsigned)f2bf(f.z) | ((unsigned)f2bf(f.w) << 16);
  reinterpret_cast<uint2*>(dst)[li] = u;
}

// ---------- 2a. generic bf16 GEMM  C[M,N] = A[M,K] @ B[N,K]^T (+bias), bf16 out ----------
__global__ __launch_bounds__(256) void gemm_abt_bf16(
    const unsigned short* __restrict__ A,
    const unsigned short* __restrict__ B,
    unsigned short* __restrict__ C,
    const float* __restrict__ bias,
    int K, int lda, int ldb, int ldc)
{
  __shared__ unsigned short As[64][40];   // +8 pad
  __shared__ unsigned short Bs[64][40];
  const int m0 = blockIdx.y * 64, n0 = blockIdx.x * 64;
  const int tid = threadIdx.x;
  const int lane = tid & 63, w = tid >> 6;
  const int wm = w >> 1, wn = w & 1;
  const int r16 = lane & 15, kg = lane >> 4;
  const int srow = tid >> 2, sseg = tid & 3;

  const f32x4 fzero = {0.f, 0.f, 0.f, 0.f};
  f32x4 acc[2][2];
#pragma unroll
  for (int i = 0; i < 2; ++i)
#pragma unroll
    for (int j = 0; j < 2; ++j) acc[i][j] = fzero;

  for (int k0 = 0; k0 < K; k0 += 32) {
    __syncthreads();
    *reinterpret_cast<int4*>(&As[srow][sseg * 8]) =
        *reinterpret_cast<const int4*>(&A[(long)(m0 + srow) * lda + k0 + sseg * 8]);
    *reinterpret_cast<int4*>(&Bs[srow][sseg * 8]) =
        *reinterpret_cast<const int4*>(&B[(long)(n0 + srow) * ldb + k0 + sseg * 8]);
    __syncthreads();
    bf16x8 a[2], b[2];
#pragma unroll
    for (int i = 0; i < 2; ++i)
      a[i] = *reinterpret_cast<const bf16x8*>(&As[wm * 32 + i * 16 + r16][kg * 8]);
#pragma unroll
    for (int j = 0; j < 2; ++j)
      b[j] = *reinterpret_cast<const bf16x8*>(&Bs[wn * 32 + j * 16 + r16][kg * 8]);
#pragma unroll
    for (int i = 0; i < 2; ++i)
#pragma unroll
      for (int j = 0; j < 2; ++j)
        acc[i][j] = __builtin_amdgcn_mfma_f32_16x16x32_bf16(a[i], b[j], acc[i][j], 0, 0, 0);
  }
#pragma unroll
  for (int i = 0; i < 2; ++i) {
#pragma unroll
    for (int j = 0; j < 2; ++j) {
      const int row = m0 + wm * 32 + i * 16 + kg * 4;
      const int col = n0 + wn * 32 + j * 16 + r16;
      const float bv = bias ? bias[col] : 0.f;
#pragma unroll
      for (int r = 0; r < 4; ++r)
        C[(long)(row + r) * ldc + col] = f2bf(acc[i][j][r] + bv);
    }
  }
}

// ---------- 2b. fused K/V projection: blockIdx.z selects (B,C,bias) ----------
__global__ __launch_bounds__(256) void gemm_abt_bf16_kv(
    const unsigned short* __restrict__ A,
    const unsigned short* __restrict__ B0,
    const unsigned short* __restrict__ B1,
    unsigned short* __restrict__ C0,
    unsigned short* __restrict__ C1,
    const float* __restrict__ bias0,
    const float* __restrict__ bias1,
    int K, int lda, int ldb, int ldc)
{
  const unsigned short* B = blockIdx.z ? B1 : B0;
  unsigned short* C = blockIdx.z ? C1 : C0;
  const float* bias = blockIdx.z ? bias1 : bias0;

  __shared__ unsigned short As[64][40];
  __shared__ unsigned short Bs[64][40];
  const int m0 = blockIdx.y * 64, n0 = blockIdx.x * 64;
  const int tid = threadIdx.x;
  const int lane = tid & 63, w = tid >> 6;
  const int wm = w >> 1, wn = w & 1;
  const int r16 = lane & 15, kg = lane >> 4;
  const int srow = tid >> 2, sseg = tid & 3;

  const f32x4 fzero = {0.f, 0.f, 0.f, 0.f};
  f32x4 acc[2][2];
#pragma unroll
  for (int i = 0; i < 2; ++i)
#pragma unroll
    for (int j = 0; j < 2; ++j) acc[i][j] = fzero;

  for (int k0 = 0; k0 < K; k0 += 32) {
    __syncthreads();
    *reinterpret_cast<int4*>(&As[srow][sseg * 8]) =
        *reinterpret_cast<const int4*>(&A[(long)(m0 + srow) * lda + k0 + sseg * 8]);
    *reinterpret_cast<int4*>(&Bs[srow][sseg * 8]) =
        *reinterpret_cast<const int4*>(&B[(long)(n0 + srow) * ldb + k0 + sseg * 8]);
    __syncthreads();
    bf16x8 a[2], b[2];
#pragma unroll
    for (int i = 0; i < 2; ++i)
      a[i] = *reinterpret_cast<const bf16x8*>(&As[wm * 32 + i * 16 + r16][kg * 8]);
#pragma unroll
    for (int j = 0; j < 2; ++j)
      b[j] = *reinterpret_cast<const bf16x8*>(&Bs[wn * 32 + j * 16 + r16][kg * 8]);
#pragma unroll
    for (int i = 0; i < 2; ++i)
#pragma unroll
      for (int j = 0; j < 2; ++j)
        acc[i][j] = __builtin_amdgcn_mfma_f32_16x16x32_bf16(a[i], b[j], acc[i][j], 0, 0, 0);
  }
#pragma unroll
  for (int i = 0; i < 2; ++i) {
#pragma unroll
    for (int j = 0; j < 2; ++j) {
      const int row = m0 + wm * 32 + i * 16 + kg * 4;
      const int col = n0 + wn * 32 + j * 16 + r16;
      const float bv = bias ? bias[col] : 0.f;
#pragma unroll
      for (int r = 0; r < 4; ++r)
        C[(long)(row + r) * ldc + col] = f2bf(acc[i][j][r] + bv);
    }
  }
}

// ---------- 3. scores + softmax over frames -> P[v][t][f*16+h] (bf16) ----------
__global__ __launch_bounds__(256) void scores_softmax(
    const unsigned short* __restrict__ Kp,   // [v*12][1024] = [v][f][h*64+d]
    const unsigned short* __restrict__ Qp,   // [256][1024]  = [t][h*64+d]
    unsigned short* __restrict__ P)          // [v][256][192]
{
  const int h = blockIdx.x, v = blockIdx.y;
  const int tid = threadIdx.x, lane = tid & 63, w = tid >> 6;
  const int r16 = lane & 15, kg = lane >> 4;
  __shared__ unsigned short Ks[16][72];
  __shared__ unsigned short Qs[256][72];

  if (tid < 96) {
    const int f = tid >> 3, seg = tid & 7;
    *reinterpret_cast<int4*>(&Ks[f][seg * 8]) =
        *reinterpret_cast<const int4*>(&Kp[(long)(v * 12 + f) * 1024 + h * 64 + seg * 8]);
  } else if (tid < 128) {   // zero-fill pad rows 12..15
    const int f = 12 + ((tid - 96) >> 3), seg = (tid - 96) & 7;
    int4 z; z.x = 0; z.y = 0; z.z = 0; z.w = 0;
    *reinterpret_cast<int4*>(&Ks[f][seg * 8]) = z;
  }
#pragma unroll
  for (int rep = 0; rep < 8; ++rep) {
    const int row = rep * 32 + (tid >> 3), seg = tid & 7;
    *reinterpret_cast<int4*>(&Qs[row][seg * 8]) =
        *reinterpret_cast<const int4*>(&Qp[(long)row * 1024 + h * 64 + seg * 8]);
  }
  __syncthreads();

  const f32x4 fzero = {0.f, 0.f, 0.f, 0.f};
  f32x4 acc[4];
#pragma unroll
  for (int j = 0; j < 4; ++j) acc[j] = fzero;

#pragma unroll
  for (int kk = 0; kk < 64; kk += 32) {
    bf16x8 a = *reinterpret_cast<const bf16x8*>(&Ks[r16][kk + kg * 8]);
#pragma unroll
    for (int j = 0; j < 4; ++j) {
      bf16x8 b = *reinterpret_cast<const bf16x8*>(&Qs[w * 64 + j * 16 + r16][kk + kg * 8]);
      acc[j] = __builtin_amdgcn_mfma_f32_16x16x32_bf16(a, b, acc[j], 0, 0, 0);
    }
  }
#pragma unroll
  for (int j = 0; j < 4; ++j) {
    float lm = -1e30f;
    if (kg < 3) {
#pragma unroll
      for (int r = 0; r < 4; ++r) lm = fmaxf(lm, acc[j][r] * 0.125f);
    }
    lm = fmaxf(lm, __shfl_xor(lm, 16));
    lm = fmaxf(lm, __shfl_xor(lm, 32));
    float p[4]; float ls = 0.f;
    if (kg < 3) {
#pragma unroll
      for (int r = 0; r < 4; ++r) { p[r] = __expf(acc[j][r] * 0.125f - lm); ls += p[r]; }
    }
    ls += __shfl_xor(ls, 16);
    ls += __shfl_xor(ls, 32);
    const float inv = 1.f / ls;
    if (kg < 3) {
      const int t = w * 64 + j * 16 + r16;
#pragma unroll
      for (int r = 0; r < 4; ++r)
        P[((long)v * 256 + t) * 192 + (kg * 4 + r) * 16 + h] = f2bf(p[r] * inv);
    }
  }
}

// ---------- 4. fused Zh + combine ----------
// Phase 1: BARRIER-FREE. A/B fragments for the Zh MFMA are direct row-major
// global reads (VP row f = lane r16; Wo row o = lane r16) — no LDS staging.
// Wave w handles h = 4w..4w+3; results -> BsAll[64 o][192 k] (T2-swizzled).
// Phase 2: one barrier; P a-frags from global (1-deep SW pipeline), b from LDS.
// LDS = 24 KB -> 6 blocks/CU.
__global__ __launch_bounds__(256) void combine(
    const unsigned short* __restrict__ VPp,  // [v*12][1024] = [v][f][h*64+d]
    const unsigned short* __restrict__ Wo,   // [1024][1024] bf16
    const unsigned short* __restrict__ P,    // [v][256][192]
    const float* __restrict__ bo,
    float* __restrict__ out)                 // [v][256][1024]
{
  // XCD-aware bijective swizzle: 4096 = 8 xcd * 32 vgrp * 16 otile
  const int wgid = blockIdx.x;
  const int xcd = wgid & 7, idx = wgid >> 3;
  const int v = ((idx & 31) << 3) | xcd;
  const int n0 = (idx >> 5) << 6;

  const int tid = threadIdx.x, lane = tid & 63, w = tid >> 6;
  const int r16 = lane & 15, kg = lane >> 4;

  __shared__ unsigned short BsAll[64 * 192];   // [o][k] swizzled, 24 KB

  // ---- phase 1: Zh slice, no barriers ----
  const unsigned short* VPv = VPp + (long)v * 12 * 1024;
#pragma unroll
  for (int hi = 0; hi < 4; ++hi) {
    const int h = (w << 2) + hi;
    const int db = h * 64;
    f32x4 accp[4] = {{0.f,0.f,0.f,0.f},{0.f,0.f,0.f,0.f},{0.f,0.f,0.f,0.f},{0.f,0.f,0.f,0.f}};
#pragma unroll
    for (int kk = 0; kk < 64; kk += 32) {
      bf16x8 a = {0,0,0,0,0,0,0,0};
      if (r16 < 12)
        a = *reinterpret_cast<const bf16x8*>(&VPv[(long)r16 * 1024 + db + kk + kg * 8]);
      bf16x8 bfr[4];
#pragma unroll
      for (int j = 0; j < 4; ++j)
        bfr[j] = *reinterpret_cast<const bf16x8*>(
            &Wo[(long)(n0 + j * 16 + r16) * 1024 + db + kk + kg * 8]);
#pragma unroll
      for (int j = 0; j < 4; ++j)
        accp[j] = __builtin_amdgcn_mfma_f32_16x16x32_bf16(a, bfr[j], accp[j], 0, 0, 0);
    }
    // D rows f = kg*4+r (keep f<12), col o = j*16+r16; k = f*16+h
#pragma unroll
    for (int j = 0; j < 4; ++j) {
#pragma unroll
      for (int r = 0; r < 4; ++r) {
        const int f = kg * 4 + r;
        if (f < 12) {
          const int o = j * 16 + r16;
          const int k = f * 16 + h;
          BsAll[o * 192 + (((k >> 3) ^ (o & 7)) << 3) + (k & 7)] = f2bf(accp[j][r]);
        }
      }
    }
  }

  // prefetch first phase-2 a-frags while phase-1 tail drains
  const unsigned short* Pv = P + (long)v * 256 * 192;
  bf16x8 aP[4];
#pragma unroll
  for (int i = 0; i < 4; ++i)
    aP[i] = *reinterpret_cast<const bf16x8*>(
        &Pv[(long)(w * 64 + i * 16 + r16) * 192 + kg * 8]);

  __syncthreads();

  // ---- phase 2: out tile = P_v @ BsAll^T ----
  f32x4 acc[4][4];
#pragma unroll
  for (int i = 0; i < 4; ++i)
#pragma unroll
    for (int j = 0; j < 4; ++j) { f32x4 z = {0.f,0.f,0.f,0.f}; acc[i][j] = z; }

#pragma unroll
  for (int k0 = 0; k0 < 192; k0 += 32) {
    bf16x8 aC[4];
#pragma unroll
    for (int i = 0; i < 4; ++i) aC[i] = aP[i];
    if (k0 < 160) {   // 1-deep pipeline: issue next k-step's loads now
#pragma unroll
      for (int i = 0; i < 4; ++i)
        aP[i] = *reinterpret_cast<const bf16x8*>(
            &Pv[(long)(w * 64 + i * 16 + r16) * 192 + (k0 + 32) + kg * 8]);
    }
    bf16x8 b[4];
#pragma unroll
    for (int j = 0; j < 4; ++j) {
      const int row = j * 16 + r16;
      const int slot = (k0 >> 3) + kg;
      b[j] = *reinterpret_cast<const bf16x8*>(
          &BsAll[row * 192 + ((slot ^ (row & 7)) << 3)]);
    }
#pragma unroll
    for (int i = 0; i < 4; ++i)
#pragma unroll
      for (int j = 0; j < 4; ++j)
        acc[i][j] = __builtin_amdgcn_mfma_f32_16x16x32_bf16(aC[i], b[j], acc[i][j], 0, 0, 0);
  }
#pragma unroll
  for (int i = 0; i < 4; ++i) {
#pragma unroll
    for (int j = 0; j < 4; ++j) {
      const int trow = w * 64 + i * 16 + kg * 4;
      const int col = n0 + j * 16 + r16;
      const float bv = bo[col];
#pragma unroll
      for (int r = 0; r < 4; ++r)
        out[((long)v * 256 + trow + r) * 1024 + col] = acc[i][j][r] + bv;
    }
  }
}

// ---------- launch ----------
extern "C" void kernel_launch(void* const* d_in, const int* in_sizes, int n_in,
                              void* d_out, int out_size, void* d_ws, size_t ws_size,
                              hipStream_t stream) {
  const float* text = (const float*)d_in[0];
  const float* vis  = (const float*)d_in[1];
  const float* wq   = (const float*)d_in[2];
  const float* bq   = (const float*)d_in[3];
  const float* wk   = (const float*)d_in[4];
  const float* bk   = (const float*)d_in[5];
  const float* wv   = (const float*)d_in[6];
  const float* bv   = (const float*)d_in[7];
  const float* wo   = (const float*)d_in[8];
  const float* bo   = (const float*)d_in[9];
  float* out = (float*)d_out;

  unsigned short* text16 = (unsigned short*)d_ws;      // 262144
  unsigned short* vis16  = text16 + 262144;            // 3145728
  unsigned short* wq16   = vis16  + 3145728;           // 1048576
  unsigned short* wk16   = wq16   + 1048576;           // 1048576
  unsigned short* wv16   = wk16   + 1048576;           // 1048576
  unsigned short* wo16   = wv16   + 1048576;           // 1048576
  unsigned short* q16    = wo16   + 1048576;           // 262144
  unsigned short* k16    = q16    + 262144;            // 3145728
  unsigned short* vp16   = k16    + 3145728;           // 3145728
  unsigned short* P      = vp16   + 3145728;           // 12582912  (total ~51 MB)

  cvt_all<<<7424, 256, 0, stream>>>(text, vis, wq, wk, wv, wo,
                                    text16, vis16, wq16, wk16, wv16, wo16);
  gemm_abt_bf16<<<dim3(16, 4), 256, 0, stream>>>(text16, wq16, q16, bq, 1024, 1024, 1024, 1024);
  gemm_abt_bf16_kv<<<dim3(16, 48, 2), 256, 0, stream>>>(
      vis16, wk16, wv16, k16, vp16, bk, bv, 1024, 1024, 1024, 1024);
  scores_softmax<<<dim3(16, 256), 256, 0, stream>>>(k16, q16, P);
  combine<<<4096, 256, 0, stream>>>(vp16, wo16, P, bo, out);
}